// Round 4
// baseline (498.875 us; speedup 1.0000x reference)
//
#include <hip/hip_runtime.h>

typedef _Float16 f16x8  __attribute__((ext_vector_type(8)));
typedef float    f32x4  __attribute__((ext_vector_type(4)));
typedef float    f32x16 __attribute__((ext_vector_type(16)));

#define MROWS 16384
#define NCOLS 256
#define KDIM  4096
#define BM    128
#define BK    32
#define LDA   34   // f16 stride per A row in LDS: 68 B -> granule stride 17 (odd) => 2-way max (free)

// out layout (floats): idx[32768] | scores[32768] | pf[1048576] | imp[64] | load[64]
#define OUT_SCORES 32768
#define OUT_PF     65536
#define OUT_IMP    1114112
#define OUT_LOAD   1114176

#define FIN_BLOCKS 1024

// ---------------- Kernel 1: W fp32 -> frag-major f16 hi/lo planes (32x32x16 layout) ----
// B-frag for mfma_f32_32x32x16_f16: lane = (n&31) + 32*((k>>3)&1), j = k&7,
// ksub = (k>>4)&1, NT = n>>5, ksg = k>>5.
// flat: (((ksg*8 + NT)*2 + ksub)*64 + lane)*8 + j
__global__ __launch_bounds__(256) void wprep(const float* __restrict__ W,
                                             _Float16* __restrict__ wfHi,
                                             _Float16* __restrict__ wfLo) {
    int t  = blockIdx.x * 256 + threadIdx.x;   // 131072 threads: 256 n x 512 k8
    int n  = t >> 9;
    int k8 = t & 511;                          // 8 consecutive k starting at k8*8
    const float* src = W + ((size_t)n * KDIM + (size_t)k8 * 8);
    f16x8 hi, lo;
#pragma unroll
    for (int j = 0; j < 8; ++j) {
        float x = src[j];
        _Float16 h = (_Float16)x;
        hi[j] = h;
        lo[j] = (_Float16)(x - (float)h);
    }
    int NT    = n >> 5;
    int ksg   = k8 >> 2;
    int ksub  = (k8 >> 1) & 1;
    int lane  = (n & 31) + ((k8 & 1) << 5);
    size_t dst = ((size_t)((ksg * 8 + NT) * 2 + ksub) * 64 + (size_t)lane) * 8;
    *(f16x8*)(wfHi + dst) = hi;
    *(f16x8*)(wfLo + dst) = lo;
}

// ---------------- Kernel 2: occupancy-first f16x2-split GEMM, 32x32x16 MFMA ----------
// grid = 128*nsplit blocks x 512 threads (8 waves = 2 row-groups x 4 col-groups).
// Per wave: 2mi x 2ni 32x32 tiles -> acc = 4 x f32x16 = 64 VGPRs, so
// __launch_bounds__(512,4) fits 2 blocks/CU = 16 waves/CU = 4 waves/SIMD (2x round-3).
// Latency hiding comes from TLP, not schedule: B loads post-barrier, X depth-1 prefetch.
__global__ __launch_bounds__(512, 4) void gemm3(const float* __restrict__ X,
        const _Float16* __restrict__ wfHi, const _Float16* __restrict__ wfLo,
        float* __restrict__ lsplit, int kQ) {
    __shared__ _Float16 aHi[2][BM * LDA];
    __shared__ _Float16 aLo[2][BM * LDA];

    const int tid  = threadIdx.x;
    const int lane = tid & 63;
    const int w    = tid >> 6;          // 0..7
    const int wr   = w >> 2;            // row-group 0..1 (64 rows each)
    const int wc   = w & 3;             // col-group 0..3 (64 cols each)
    const int mt   = blockIdx.x & 127;
    const int s    = blockIdx.x >> 7;
    const int m0   = mt * BM;
    const int k0   = s * kQ;
    const int iters = kQ / BK;

    f32x16 acc[2][2];
#pragma unroll
    for (int a = 0; a < 2; ++a)
#pragma unroll
        for (int b = 0; b < 2; ++b)
#pragma unroll
            for (int q = 0; q < 16; ++q) acc[a][b][q] = 0.f;

    // staging: thread -> (row = tid>>2, quarter = tid&3 covering 8 floats)
    const int sr = tid >> 2;
    const int sq = tid & 3;
    const float* xrow = X + ((size_t)(m0 + sr) * KDIM + (size_t)k0 + sq * 8);
    const int woff = sr * LDA + sq * 8;

    // A frag read base: row = wr*64 + mi*32 + (lane&31), k-granule (lane>>5)*8
    const int roff = (wr * 64 + (lane & 31)) * LDA + (lane >> 5) * 8;

    // B frag base: flat = ksg*8192 + NT*1024 + ksub*512 + lane*8, NT = 2*wc + ni
    const size_t bbase = (size_t)(k0 >> 5) * 8192 + (size_t)(2 * wc) * 1024 + (size_t)lane * 8;
    const _Float16* BH = wfHi + bbase;
    const _Float16* BL = wfLo + bbase;

    // prologue: X(0) into regs
    f32x4 xq0 = *(const f32x4*)(xrow);
    f32x4 xq1 = *(const f32x4*)(xrow + 4);

    for (int i = 0; i < iters; ++i) {
        // issue X(i+1) prefetch (stays in flight across the barrier; last iter
        // re-reads iter 0's span -- in-bounds, discarded)
        f32x4 xn0, xn1;
        {
            const float* xp = xrow + (size_t)((i + 1 < iters) ? (i + 1) : 0) * BK;
            xn0 = *(const f32x4*)(xp);
            xn1 = *(const f32x4*)(xp + 4);
        }

        // split-convert X(i): 8 floats -> hi/lo f16x8
        float xv[8];
        xv[0] = xq0[0]; xv[1] = xq0[1]; xv[2] = xq0[2]; xv[3] = xq0[3];
        xv[4] = xq1[0]; xv[5] = xq1[1]; xv[6] = xq1[2]; xv[7] = xq1[3];
        f16x8 h, l;
#pragma unroll
        for (int j = 0; j < 8; ++j) {
            _Float16 ha = (_Float16)xv[j];
            h[j] = ha;
            l[j] = (_Float16)(xv[j] - (float)ha);
        }

        // write this iter's LDS buffer
        *(f16x8*)(&aHi[i & 1][woff]) = h;
        *(f16x8*)(&aLo[i & 1][woff]) = l;

        // raw barrier: drain LDS ops only -- global X prefetch stays in flight
        asm volatile("s_waitcnt lgkmcnt(0)" ::: "memory");
        __builtin_amdgcn_s_barrier();
        __builtin_amdgcn_sched_barrier(0);

        // B frags post-barrier (keeps reg peak under the 128 cap; TLP hides L2 hit)
        f16x8 bH[2][2], bL[2][2];
#pragma unroll
        for (int ni = 0; ni < 2; ++ni)
#pragma unroll
            for (int ks = 0; ks < 2; ++ks) {
                size_t off = (size_t)i * 8192 + (size_t)ni * 1024 + (size_t)ks * 512;
                bH[ni][ks] = *(const f16x8*)(BH + off);
                bL[ni][ks] = *(const f16x8*)(BL + off);
            }

        const _Float16* rAH = &aHi[i & 1][roff];
        const _Float16* rAL = &aLo[i & 1][roff];
        __builtin_amdgcn_s_setprio(1);
#pragma unroll
        for (int mi = 0; mi < 2; ++mi) {
            f16x8 aH0 = *(const f16x8*)(rAH + mi * 32 * LDA);
            f16x8 aH1 = *(const f16x8*)(rAH + mi * 32 * LDA + 16);
            f16x8 aL0 = *(const f16x8*)(rAL + mi * 32 * LDA);
            f16x8 aL1 = *(const f16x8*)(rAL + mi * 32 * LDA + 16);
#pragma unroll
            for (int ni = 0; ni < 2; ++ni) {
                acc[mi][ni] = __builtin_amdgcn_mfma_f32_32x32x16_f16(aH0, bH[ni][0], acc[mi][ni], 0, 0, 0);
                acc[mi][ni] = __builtin_amdgcn_mfma_f32_32x32x16_f16(aH1, bH[ni][1], acc[mi][ni], 0, 0, 0);
                acc[mi][ni] = __builtin_amdgcn_mfma_f32_32x32x16_f16(aH0, bL[ni][0], acc[mi][ni], 0, 0, 0);
                acc[mi][ni] = __builtin_amdgcn_mfma_f32_32x32x16_f16(aH1, bL[ni][1], acc[mi][ni], 0, 0, 0);
                acc[mi][ni] = __builtin_amdgcn_mfma_f32_32x32x16_f16(aL0, bH[ni][0], acc[mi][ni], 0, 0, 0);
                acc[mi][ni] = __builtin_amdgcn_mfma_f32_32x32x16_f16(aL1, bH[ni][1], acc[mi][ni], 0, 0, 0);
            }
        }
        __builtin_amdgcn_s_setprio(0);

        // rotate prefetch regs
        xq0 = xn0; xq1 = xn1;
    }

    // epilogue: partial logits. 32x32 C/D: col = lane&31,
    // row = (reg&3) + 8*(reg>>2) + 4*(lane>>5)   (m74/m101)
    float* outp = lsplit + (size_t)s * ((size_t)MROWS * NCOLS);
#pragma unroll
    for (int mi = 0; mi < 2; ++mi) {
#pragma unroll
        for (int ni = 0; ni < 2; ++ni) {
            int col   = wc * 64 + ni * 32 + (lane & 31);
            int rbase = m0 + wr * 64 + mi * 32 + ((lane >> 5) << 2);
#pragma unroll
            for (int reg = 0; reg < 16; ++reg) {
                int row = rbase + (reg & 3) + ((reg >> 2) << 3);
                outp[(size_t)row * NCOLS + col] = acc[mi][ni][reg];
            }
        }
    }
}

// ---------------- Kernel 3: softmax / head-mean / top-2 / aux partials ----------------
// 16 lanes per row; lane i holds flat logits f = i + 16*t, t=0..15 (head g = t>>2,
// expert e = i + 16*(t&3) -> all 4 head values of an expert live in one lane).
// Aux stats: per-block LDS aggregation -> ONE coalesced 512B partial store per block.
__global__ __launch_bounds__(256) void finalize(const float* __restrict__ lsplit,
                                                int nsplit, float* __restrict__ out,
                                                float* __restrict__ paux) {
    __shared__ float sImp[64], sLoad[64];
    const int tid = threadIdx.x;
    if (tid < 64) { sImp[tid] = 0.f; sLoad[tid] = 0.f; }
    __syncthreads();

    const int i   = tid & 15;
    const int grp = tid >> 4;
    const int r   = blockIdx.x * 16 + grp;

    float v[16];
#pragma unroll
    for (int t = 0; t < 16; ++t) {
        size_t off = (size_t)r * 256 + (size_t)i + 16 * t;
        float a = lsplit[off];
        for (int s = 1; s < nsplit; ++s)
            a += lsplit[(size_t)s * ((size_t)MROWS * NCOLS) + off];
        v[t] = a;
    }

    float hm[4];
#pragma unroll
    for (int g = 0; g < 4; ++g) {
        float m = fmaxf(fmaxf(v[4*g], v[4*g+1]), fmaxf(v[4*g+2], v[4*g+3]));
#pragma unroll
        for (int msk = 1; msk < 16; msk <<= 1)
            m = fmaxf(m, __shfl_xor(m, msk));
        hm[g] = m;
    }
    float p[16], inv[4];
#pragma unroll
    for (int g = 0; g < 4; ++g) {
        float sa = 0.f;
#pragma unroll
        for (int q = 0; q < 4; ++q) { p[4*g+q] = __expf(v[4*g+q] - hm[g]); sa += p[4*g+q]; }
#pragma unroll
        for (int msk = 1; msk < 16; msk <<= 1)
            sa += __shfl_xor(sa, msk);
        inv[g] = 1.f / sa;
    }

    float pf[4];
#pragma unroll
    for (int et = 0; et < 4; ++et) {
        pf[et] = 0.25f * (p[et] * inv[0] + p[4+et] * inv[1] + p[8+et] * inv[2] + p[12+et] * inv[3]);
        out[OUT_PF + (size_t)r * 64 + i + 16 * et] = pf[et];
        atomicAdd(&sImp[i + 16 * et], pf[et]);
        atomicAdd(&sLoad[i + 16 * et], pf[et] > 0.f ? 1.f : 0.f);
    }

    // top-2 with jax tie-break (equal value -> lower index)
    float v1 = -3.4e38f, v2 = -3.4e38f; int e1 = 0, e2 = 0;
#pragma unroll
    for (int et = 0; et < 4; ++et) {
        int e = i + 16 * et; float val = pf[et];
        if (val > v1) { v2 = v1; e2 = e1; v1 = val; e1 = e; }
        else if (val > v2) { v2 = val; e2 = e; }
    }
#pragma unroll
    for (int msk = 1; msk < 16; msk <<= 1) {
        float o1 = __shfl_xor(v1, msk); int oe1 = __shfl_xor(e1, msk);
        float o2 = __shfl_xor(v2, msk); int oe2 = __shfl_xor(e2, msk);
        bool ob = (o1 > v1) || (o1 == v1 && oe1 < e1);
        if (ob) {
            bool vb = (v1 > o2) || (v1 == o2 && e1 < oe2);
            v2 = vb ? v1 : o2; e2 = vb ? e1 : oe2;
            v1 = o1; e1 = oe1;
        } else {
            bool nb = (o1 > v2) || (o1 == v2 && oe1 < e2);
            v2 = nb ? o1 : v2; e2 = nb ? oe1 : e2;
        }
    }
    if (i == 0) {
        float den = fmaxf(v1 + v2, 1e-9f);
        out[(size_t)r * 2]              = (float)e1;
        out[(size_t)r * 2 + 1]          = (float)e2;
        out[OUT_SCORES + (size_t)r * 2]     = v1 / den;
        out[OUT_SCORES + (size_t)r * 2 + 1] = v2 / den;
    }
    __syncthreads();
    if (tid < 128)
        paux[(size_t)blockIdx.x * 128 + tid] = (tid < 64) ? sImp[tid] : sLoad[tid - 64];
}

// ---------------- Kernel 4: reduce per-block aux partials -> imp/load ----------------
// 1 block x 1024 threads: 8 strip-parallel groups + LDS combine (deterministic).
__global__ __launch_bounds__(1024) void reduce_aux(const float* __restrict__ paux,
                                                   float* __restrict__ out) {
    __shared__ float part[8][128];
    const int t = threadIdx.x & 127;
    const int g = threadIdx.x >> 7;
    float s = 0.f;
    for (int b = g * 128; b < g * 128 + 128; ++b)
        s += paux[(size_t)b * 128 + t];
    part[g][t] = s;
    __syncthreads();
    if (threadIdx.x < 128) {
        float a = 0.f;
#pragma unroll
        for (int g2 = 0; g2 < 8; ++g2) a += part[g2][t];
        out[OUT_IMP + t] = a * (1.0f / 16384.0f);
    }
}

extern "C" void kernel_launch(void* const* d_in, const int* in_sizes, int n_in,
                              void* d_out, int out_size, void* d_ws, size_t ws_size,
                              hipStream_t stream) {
    const float* X = (const float*)d_in[0];
    const float* W = (const float*)d_in[1];
    float* out = (float*)d_out;
    char* ws = (char*)d_ws;

    _Float16* wfHi = (_Float16*)ws;
    _Float16* wfLo = (_Float16*)(ws + (2u << 20));
    float* lsplit  = (float*)(ws + (4u << 20));

    const size_t per = 16u << 20;                       // one logits partial buffer
    int nsplit = (ws_size >= (4u << 20) + 4 * per + (1u << 20)) ? 4
               : (ws_size >= (4u << 20) + 2 * per + (1u << 20)) ? 2 : 1;

    float* paux = (float*)(ws + (4u << 20) + (size_t)nsplit * per);

    wprep<<<512, 256, 0, stream>>>(W, wfHi, wfLo);
    gemm3<<<128 * nsplit, 512, 0, stream>>>(X, wfHi, wfLo, lsplit, KDIM / nsplit);
    finalize<<<FIN_BLOCKS, 256, 0, stream>>>(lsplit, nsplit, out, paux);
    reduce_aux<<<1, 1024, 0, stream>>>(paux, out);
}

// Round 5
// 491.325 us; speedup vs baseline: 1.0154x; 1.0154x over previous
//
#include <hip/hip_runtime.h>

typedef _Float16 f16x8  __attribute__((ext_vector_type(8)));
typedef float    f32x4  __attribute__((ext_vector_type(4)));
typedef float    f32x16 __attribute__((ext_vector_type(16)));

#define MROWS 16384
#define NCOLS 256
#define KDIM  4096
#define BM    128
#define BK    32
#define BKO   128  // outer K-tile: 512 B contiguous per row per fetch burst (DRAM-friendly)
#define LDA   34   // f16 row stride = 17 dwords (ODD) -> writes (17r+8q)%32 and reads (17r+4s)%32 both exact 2-way = free

// out layout (floats): idx[32768] | scores[32768] | pf[1048576] | imp[64] | load[64]
#define OUT_SCORES 32768
#define OUT_PF     65536
#define OUT_IMP    1114112
#define OUT_LOAD   1114176

#define FIN_BLOCKS 1024

// ---------------- Kernel 1: W fp32 -> frag-major f16 hi/lo planes (32x32x16 layout) ----
// B-frag for mfma_f32_32x32x16_f16: lane = (n&31) + 32*((k>>3)&1), j = k&7,
// ksub = (k>>4)&1, NT = n>>5, ksg = k>>5.
// flat: (((ksg*8 + NT)*2 + ksub)*64 + lane)*8 + j
__global__ __launch_bounds__(256) void wprep(const float* __restrict__ W,
                                             _Float16* __restrict__ wfHi,
                                             _Float16* __restrict__ wfLo) {
    int t  = blockIdx.x * 256 + threadIdx.x;   // 131072 threads: 256 n x 512 k8
    int n  = t >> 9;
    int k8 = t & 511;                          // 8 consecutive k starting at k8*8
    const float* src = W + ((size_t)n * KDIM + (size_t)k8 * 8);
    f16x8 hi, lo;
#pragma unroll
    for (int j = 0; j < 8; ++j) {
        float x = src[j];
        _Float16 h = (_Float16)x;
        hi[j] = h;
        lo[j] = (_Float16)(x - (float)h);
    }
    int NT    = n >> 5;
    int ksg   = k8 >> 2;
    int ksub  = (k8 >> 1) & 1;
    int lane  = (n & 31) + ((k8 & 1) << 5);
    size_t dst = ((size_t)((ksg * 8 + NT) * 2 + ksub) * 64 + (size_t)lane) * 8;
    *(f16x8*)(wfHi + dst) = hi;
    *(f16x8*)(wfLo + dst) = lo;
}

// ---------------- Kernel 2: DRAM-burst f16x2-split GEMM, 32x32x16 MFMA ----------------
// grid = 128*nsplit x 512 threads (8 waves = 2 row-groups x 4 col-groups), 1 block/CU.
// Outer loop stages BKO=128 K-columns of X into registers as ONE contiguous 512B-per-row
// burst (fixes the 128B-granule DRAM row-thrash that capped HBM at 1.2 TB/s in r0-r4).
// Inner 4x BK=32 passes: convert 8 floats/thread -> hi/lo LDS tile -> 24 MFMA/wave.
// B frags depth-1 prefetched (latency off the critical path). X depth-1 via stash reuse.
__global__ __launch_bounds__(512, 2) void gemm3(const float* __restrict__ X,
        const _Float16* __restrict__ wfHi, const _Float16* __restrict__ wfLo,
        float* __restrict__ lsplit, int kQ) {
    __shared__ _Float16 aHi[2][BM * LDA];
    __shared__ _Float16 aLo[2][BM * LDA];

    const int tid  = threadIdx.x;
    const int lane = tid & 63;
    const int w    = tid >> 6;          // 0..7
    const int wr   = w >> 2;            // row-group 0..1 (64 rows each)
    const int wc   = w & 3;             // col-group 0..3 (64 cols each)
    const int mt   = blockIdx.x & 127;
    const int s    = blockIdx.x >> 7;
    const int m0   = mt * BM;
    const int k0   = s * kQ;
    const int outers = kQ >> 7;         // BKO=128 per outer

    f32x16 acc[2][2];
#pragma unroll
    for (int a = 0; a < 2; ++a)
#pragma unroll
        for (int b = 0; b < 2; ++b)
#pragma unroll
            for (int qq = 0; qq < 16; ++qq) acc[a][b][qq] = 0.f;

    // staging: thread -> row rr = tid>>2 (4 threads/row), q = tid&3 owns cols q*8..q*8+7
    // of each inner BK=32 chunk. Global burst per outer: 8 x f32x4 covering the thread's
    // 4x8 floats; a 4-lane row-group covers 512 B contiguous issued back-to-back.
    const int rr = tid >> 2;
    const int q  = tid & 3;
    const float* xbase = X + ((size_t)(m0 + rr) * KDIM + (size_t)k0 + (size_t)q * 8);
    const int woff = rr * LDA + q * 8;

    // A frag read base: row = wr*64 + mi*32 + (lane&31), k-granule (lane>>5)*8
    const int roff = (wr * 64 + (lane & 31)) * LDA + (lane >> 5) * 8;

    // B frag base: flat = ksg*8192 + NT*1024 + ksub*512 + lane*8, NT = 2*wc + ni
    const size_t bbase = (size_t)(k0 >> 5) * 8192 + (size_t)(2 * wc) * 1024 + (size_t)lane * 8;
    const _Float16* pBH = wfHi + bbase;
    const _Float16* pBL = wfLo + bbase;

    // prologue: X stash for outer 0 (contiguous burst)
    f32x4 xs[8];
#pragma unroll
    for (int jh = 0; jh < 8; ++jh)
        xs[jh] = *(const f32x4*)(xbase + (jh >> 1) * 32 + (jh & 1) * 4);

    // prologue: B frags for inner 0
    f16x8 bH[2][2][2], bL[2][2][2];   // [buf][ni][ks] -- all indices static after unroll
#pragma unroll
    for (int ni = 0; ni < 2; ++ni)
#pragma unroll
        for (int ks = 0; ks < 2; ++ks) {
            bH[0][ni][ks] = *(const f16x8*)(pBH + ni * 1024 + ks * 512);
            bL[0][ni][ks] = *(const f16x8*)(pBL + ni * 1024 + ks * 512);
        }

    for (int o = 0; o < outers; ++o) {
#pragma unroll
        for (int j = 0; j < 4; ++j) {
            // convert this inner chunk's 8 floats -> hi/lo f16x8
            float xv[8];
            xv[0] = xs[2*j][0]; xv[1] = xs[2*j][1]; xv[2] = xs[2*j][2]; xv[3] = xs[2*j][3];
            xv[4] = xs[2*j+1][0]; xv[5] = xs[2*j+1][1]; xv[6] = xs[2*j+1][2]; xv[7] = xs[2*j+1][3];
            f16x8 h, l;
#pragma unroll
            for (int e = 0; e < 8; ++e) {
                _Float16 ha = (_Float16)xv[e];
                h[e] = ha;
                l[e] = (_Float16)(xv[e] - (float)ha);
            }

            // at last inner: issue next outer's X burst (regs free after convert above;
            // loads stay in flight across the barrier, consumed next outer's j=0)
            if (j == 3) {
                const float* xp = xbase + (size_t)((o + 1 < outers) ? (o + 1) : 0) * BKO;
#pragma unroll
                for (int jh = 0; jh < 8; ++jh)
                    xs[jh] = *(const f32x4*)(xp + (jh >> 1) * 32 + (jh & 1) * 4);
            }

            // stage this inner tile (write banks (17r+8q)%32: exact 2-way = free)
            *(f16x8*)(&aHi[j & 1][woff]) = h;
            *(f16x8*)(&aLo[j & 1][woff]) = l;

            // raw barrier: drain LDS only -- X/B global loads stay in flight
            asm volatile("s_waitcnt lgkmcnt(0)" ::: "memory");
            __builtin_amdgcn_s_barrier();
            __builtin_amdgcn_sched_barrier(0);

            // depth-1 B prefetch for next inner (wraps harmlessly at the very end)
            {
                bool lastInner = (o == outers - 1) && (j == 3);
                const _Float16* nBH = lastInner ? (wfHi + bbase) : (pBH + 8192);
                const _Float16* nBL = lastInner ? (wfLo + bbase) : (pBL + 8192);
#pragma unroll
                for (int ni = 0; ni < 2; ++ni)
#pragma unroll
                    for (int ks = 0; ks < 2; ++ks) {
                        bH[(j + 1) & 1][ni][ks] = *(const f16x8*)(nBH + ni * 1024 + ks * 512);
                        bL[(j + 1) & 1][ni][ks] = *(const f16x8*)(nBL + ni * 1024 + ks * 512);
                    }
                pBH = nBH; pBL = nBL;
            }

            // A frags from LDS + MFMA (B frags for THIS inner loaded last inner)
            const _Float16* rAH = &aHi[j & 1][roff];
            const _Float16* rAL = &aLo[j & 1][roff];
            __builtin_amdgcn_s_setprio(1);
#pragma unroll
            for (int mi = 0; mi < 2; ++mi) {
                f16x8 aH0 = *(const f16x8*)(rAH + mi * 32 * LDA);
                f16x8 aH1 = *(const f16x8*)(rAH + mi * 32 * LDA + 16);
                f16x8 aL0 = *(const f16x8*)(rAL + mi * 32 * LDA);
                f16x8 aL1 = *(const f16x8*)(rAL + mi * 32 * LDA + 16);
#pragma unroll
                for (int ni = 0; ni < 2; ++ni) {
                    acc[mi][ni] = __builtin_amdgcn_mfma_f32_32x32x16_f16(aH0, bH[j & 1][ni][0], acc[mi][ni], 0, 0, 0);
                    acc[mi][ni] = __builtin_amdgcn_mfma_f32_32x32x16_f16(aH1, bH[j & 1][ni][1], acc[mi][ni], 0, 0, 0);
                    acc[mi][ni] = __builtin_amdgcn_mfma_f32_32x32x16_f16(aH0, bL[j & 1][ni][0], acc[mi][ni], 0, 0, 0);
                    acc[mi][ni] = __builtin_amdgcn_mfma_f32_32x32x16_f16(aH1, bL[j & 1][ni][1], acc[mi][ni], 0, 0, 0);
                    acc[mi][ni] = __builtin_amdgcn_mfma_f32_32x32x16_f16(aL0, bH[j & 1][ni][0], acc[mi][ni], 0, 0, 0);
                    acc[mi][ni] = __builtin_amdgcn_mfma_f32_32x32x16_f16(aL1, bH[j & 1][ni][1], acc[mi][ni], 0, 0, 0);
                }
            }
            __builtin_amdgcn_s_setprio(0);
        }
    }

    // epilogue: partial logits. 32x32 C/D: col = lane&31,
    // row = (reg&3) + 8*(reg>>2) + 4*(lane>>5)   (m74/m101)
    float* outp = lsplit + (size_t)s * ((size_t)MROWS * NCOLS);
#pragma unroll
    for (int mi = 0; mi < 2; ++mi) {
#pragma unroll
        for (int ni = 0; ni < 2; ++ni) {
            int col   = wc * 64 + ni * 32 + (lane & 31);
            int rbase = m0 + wr * 64 + mi * 32 + ((lane >> 5) << 2);
#pragma unroll
            for (int reg = 0; reg < 16; ++reg) {
                int row = rbase + (reg & 3) + ((reg >> 2) << 3);
                outp[(size_t)row * NCOLS + col] = acc[mi][ni][reg];
            }
        }
    }
}

// ---------------- Kernel 3: softmax / head-mean / top-2 / aux partials ----------------
// 16 lanes per row; lane i holds flat logits f = i + 16*t, t=0..15 (head g = t>>2,
// expert e = i + 16*(t&3) -> all 4 head values of an expert live in one lane).
// Aux stats: per-block LDS aggregation -> ONE coalesced 512B partial store per block.
__global__ __launch_bounds__(256) void finalize(const float* __restrict__ lsplit,
                                                int nsplit, float* __restrict__ out,
                                                float* __restrict__ paux) {
    __shared__ float sImp[64], sLoad[64];
    const int tid = threadIdx.x;
    if (tid < 64) { sImp[tid] = 0.f; sLoad[tid] = 0.f; }
    __syncthreads();

    const int i   = tid & 15;
    const int grp = tid >> 4;
    const int r   = blockIdx.x * 16 + grp;

    float v[16];
#pragma unroll
    for (int t = 0; t < 16; ++t) {
        size_t off = (size_t)r * 256 + (size_t)i + 16 * t;
        float a = lsplit[off];
        for (int s = 1; s < nsplit; ++s)
            a += lsplit[(size_t)s * ((size_t)MROWS * NCOLS) + off];
        v[t] = a;
    }

    float hm[4];
#pragma unroll
    for (int g = 0; g < 4; ++g) {
        float m = fmaxf(fmaxf(v[4*g], v[4*g+1]), fmaxf(v[4*g+2], v[4*g+3]));
#pragma unroll
        for (int msk = 1; msk < 16; msk <<= 1)
            m = fmaxf(m, __shfl_xor(m, msk));
        hm[g] = m;
    }
    float p[16], inv[4];
#pragma unroll
    for (int g = 0; g < 4; ++g) {
        float sa = 0.f;
#pragma unroll
        for (int qq = 0; qq < 4; ++qq) { p[4*g+qq] = __expf(v[4*g+qq] - hm[g]); sa += p[4*g+qq]; }
#pragma unroll
        for (int msk = 1; msk < 16; msk <<= 1)
            sa += __shfl_xor(sa, msk);
        inv[g] = 1.f / sa;
    }

    float pf[4];
#pragma unroll
    for (int et = 0; et < 4; ++et) {
        pf[et] = 0.25f * (p[et] * inv[0] + p[4+et] * inv[1] + p[8+et] * inv[2] + p[12+et] * inv[3]);
        out[OUT_PF + (size_t)r * 64 + i + 16 * et] = pf[et];
        atomicAdd(&sImp[i + 16 * et], pf[et]);
        atomicAdd(&sLoad[i + 16 * et], pf[et] > 0.f ? 1.f : 0.f);
    }

    // top-2 with jax tie-break (equal value -> lower index)
    float v1 = -3.4e38f, v2 = -3.4e38f; int e1 = 0, e2 = 0;
#pragma unroll
    for (int et = 0; et < 4; ++et) {
        int e = i + 16 * et; float val = pf[et];
        if (val > v1) { v2 = v1; e2 = e1; v1 = val; e1 = e; }
        else if (val > v2) { v2 = val; e2 = e; }
    }
#pragma unroll
    for (int msk = 1; msk < 16; msk <<= 1) {
        float o1 = __shfl_xor(v1, msk); int oe1 = __shfl_xor(e1, msk);
        float o2 = __shfl_xor(v2, msk); int oe2 = __shfl_xor(e2, msk);
        bool ob = (o1 > v1) || (o1 == v1 && oe1 < e1);
        if (ob) {
            bool vb = (v1 > o2) || (v1 == o2 && e1 < oe2);
            v2 = vb ? v1 : o2; e2 = vb ? e1 : oe2;
            v1 = o1; e1 = oe1;
        } else {
            bool nb = (o1 > v2) || (o1 == v2 && oe1 < e2);
            v2 = nb ? o1 : v2; e2 = nb ? oe1 : e2;
        }
    }
    if (i == 0) {
        float den = fmaxf(v1 + v2, 1e-9f);
        out[(size_t)r * 2]              = (float)e1;
        out[(size_t)r * 2 + 1]          = (float)e2;
        out[OUT_SCORES + (size_t)r * 2]     = v1 / den;
        out[OUT_SCORES + (size_t)r * 2 + 1] = v2 / den;
    }
    __syncthreads();
    if (tid < 128)
        paux[(size_t)blockIdx.x * 128 + tid] = (tid < 64) ? sImp[tid] : sLoad[tid - 64];
}

// ---------------- Kernel 4: reduce per-block aux partials -> imp/load ----------------
// 1 block x 1024 threads: 8 strip-parallel groups + LDS combine (deterministic).
__global__ __launch_bounds__(1024) void reduce_aux(const float* __restrict__ paux,
                                                   float* __restrict__ out) {
    __shared__ float part[8][128];
    const int t = threadIdx.x & 127;
    const int g = threadIdx.x >> 7;
    float s = 0.f;
    for (int b = g * 128; b < g * 128 + 128; ++b)
        s += paux[(size_t)b * 128 + t];
    part[g][t] = s;
    __syncthreads();
    if (threadIdx.x < 128) {
        float a = 0.f;
#pragma unroll
        for (int g2 = 0; g2 < 8; ++g2) a += part[g2][t];
        out[OUT_IMP + t] = a * (1.0f / 16384.0f);
    }
}

extern "C" void kernel_launch(void* const* d_in, const int* in_sizes, int n_in,
                              void* d_out, int out_size, void* d_ws, size_t ws_size,
                              hipStream_t stream) {
    const float* X = (const float*)d_in[0];
    const float* W = (const float*)d_in[1];
    float* out = (float*)d_out;
    char* ws = (char*)d_ws;

    _Float16* wfHi = (_Float16*)ws;
    _Float16* wfLo = (_Float16*)(ws + (2u << 20));
    float* lsplit  = (float*)(ws + (4u << 20));

    const size_t per = 16u << 20;                       // one logits partial buffer
    // nsplit=2 -> grid 256 = exactly 1 block/CU
    int nsplit = (ws_size >= (4u << 20) + 2 * per + (1u << 20)) ? 2 : 1;

    float* paux = (float*)(ws + (4u << 20) + (size_t)nsplit * per);

    wprep<<<512, 256, 0, stream>>>(W, wfHi, wfLo);
    gemm3<<<128 * nsplit, 512, 0, stream>>>(X, wfHi, wfLo, lsplit, KDIM / nsplit);
    finalize<<<FIN_BLOCKS, 256, 0, stream>>>(lsplit, nsplit, out, paux);
    reduce_aux<<<1, 1024, 0, stream>>>(paux, out);
}